// Round 12
// baseline (208.843 us; speedup 1.0000x reference)
//
#include <hip/hip_runtime.h>
#include <hip/hip_bf16.h>
#include <hip/hip_cooperative_groups.h>

namespace cg = cooperative_groups;

#define B_   64
#define L_   2048
#define DTS  8
#define DSEQ 120
#define H_   64
#define TILE 64
#define NT   32          // tiles per batch row
#define NBLK 256         // 1 block/CU -> cooperative co-residency guaranteed
#define TPB  8           // tiles per block (static, balanced pairing)

typedef unsigned short u16;
typedef unsigned int   u32;
typedef __bf16 bf16x8 __attribute__((ext_vector_type(8)));
typedef short  short8 __attribute__((ext_vector_type(8)));
typedef float  f32x4  __attribute__((ext_vector_type(4)));

__device__ __forceinline__ float rrelu_f(float x) {   // slope = (1/8+1/3)/2 = 11/48
    return x >= 0.f ? x : x * 0.22916666666666666f;
}
__device__ __forceinline__ u16 f2bf(float x) {        // f32 -> bf16 bits, RNE
    unsigned u = __float_as_uint(x);
    return (u16)((u + 0x7FFFu + ((u >> 16) & 1u)) >> 16);
}
__device__ __forceinline__ float bf2f(u16 u) {
    return __uint_as_float(((unsigned)u) << 16);
}
__device__ __forceinline__ void dma16(void* lds, const void* g) {  // async global->LDS, 16B/lane
    __builtin_amdgcn_global_load_lds(
        (const __attribute__((address_space(1))) unsigned*)g,
        (__attribute__((address_space(3))) unsigned*)lds, 16, 0, 0);
}

// ---------------- single fused cooperative kernel ----------------
// Phase 0: W hi/lo pack (blocks 64-95) + qlast (blocks 0-63).  grid.sync
// Phase 1: 8 statically-paired tiles per block, double-buffered DMA staging,
//          K/V wave-specialized MFMA body (R11, verified), plain stores. grid.sync
// Phase 2: per-b combine (blocks 0-63).
__global__ __launch_bounds__(512) void fused_kernel(
    const float* __restrict__ ts, const float* __restrict__ seq,
    const int* __restrict__ lengths,
    const float* __restrict__ Wk, const float* __restrict__ bk,
    const float* __restrict__ Wq, const float* __restrict__ bq,
    const float* __restrict__ Wv, const float* __restrict__ bv,
    u16* __restrict__ packw, float* __restrict__ qlast,
    float* __restrict__ pden, float* __restrict__ pnum,
    float* __restrict__ out)
{
    cg::grid_group grid = cg::this_grid();
    const int blk = blockIdx.x, tid = threadIdx.x;
    const int wave = tid >> 6, lane = tid & 63;
    const int quad = lane >> 4, l16 = lane & 15;

    __shared__ __align__(16) float xs[2][TILE * 128];   // 2 x 32 KB, XOR-swizzled
    __shared__ float scp[TILE];
    __shared__ float red[4][H_];
    __shared__ float wd[4];

    // ================= phase 0 =================
    if (blk < 64) {
        // qlast for b = blk: 8 waves x 16 dims each, LDS reduce (xs as scratch)
        const int b = blk, part = wave, h = lane;
        const int l = lengths[b] - 1;
        const float* tsr = ts  + ((size_t)b * L_ + l) * DTS;
        const float* sqr = seq + ((size_t)b * L_ + l) * DSEQ;
        float acc = 0.f;
        const int d0 = part * 16;
        #pragma unroll
        for (int i = 0; i < 16; ++i) {
            const int d = d0 + i;
            const float xv = (d < DTS) ? tsr[d] : sqr[d - DTS];
            acc += xv * Wq[d * H_ + h];
        }
        float* qr = (float*)xs;               // 512-float scratch
        qr[part * H_ + h] = acc;
        __syncthreads();
        if (tid < H_) {
            float s = bq[tid];
            #pragma unroll
            for (int p = 0; p < 8; ++p) s += qr[p * H_ + tid];
            qlast[b * H_ + tid] = rrelu_f(s);
        }
    } else if (blk < 96) {
        // pack: packed[((ni*4+kk)*64+ln)*8+j] = W[(kk*32+(ln>>4)*8+j)*64 + ni*16+(ln&15)]
        const int f = (blk - 64) * 512 + tid;  // 0..16383
        const bool isK = f < 8192;
        const int idx = f & 8191;
        const float* W = isK ? Wk : Wv;
        u16* hi = packw + (isK ? 0 : 16384);
        u16* lo = hi + 8192;
        const int j = idx & 7, ln = (idx >> 3) & 63, kk = (idx >> 9) & 3, ni = idx >> 11;
        const int kd = kk * 32 + (ln >> 4) * 8 + j;
        const int n  = ni * 16 + (ln & 15);
        const float v = W[kd * H_ + n];
        const u16 h = f2bf(v);
        hi[idx] = h;
        lo[idx] = f2bf(v - bf2f(h));
    }
    grid.sync();

    // ================= phase 1: tiles =================
    const int w4 = wave & 3, isV = wave >> 2, m0 = w4 * 16;
    const int T = blk >> 4;                   // 0..15
    const int bb0 = (blk & 15) * 4;
    int len4[4];
    #pragma unroll
    for (int i = 0; i < 4; ++i) len4[i] = lengths[bb0 + i];   // block-uniform

    // tile slot i (0..7): b = bb0 + (i&3), t = (i<4) ? T : 31-T  (balanced pairing)
    #define SLOT_B(i) (bb0 + ((i) & 3))
    #define SLOT_T(i) (((i) < 4) ? T : (31 - T))
    #define SLOT_VALID(i) (SLOT_T(i) * TILE < len4[(i) & 3])

    // find first valid slot
    int cur = 0;
    while (cur < TPB && !SLOT_VALID(cur)) ++cur;

    if (cur < TPB) {
        // issue DMA for a tile into buffer buf
        auto issue = [&](int b, int t, int buf) {
            const float* bts = ts  + (size_t)(b * L_ + t * TILE) * DTS;
            const float* bsq = seq + (size_t)(b * L_ + t * TILE) * DSEQ;
            #pragma unroll
            for (int i = 0; i < 4; ++i) {
                const int CI = wave * 256 + i * 64 + lane;   // LDS chunk (HW: base+lane*16)
                const int row = CI >> 5, cp = CI & 31;
                const int c = cp ^ (row & 7);                // XOR-swizzled logical chunk
                char* dst = (char*)&xs[buf][0] + (size_t)(wave * 256 + i * 64) * 16;
                if (c < 2) dma16(dst, bts + (size_t)row * DTS  + c * 4);
                else       dma16(dst, bsq + (size_t)row * DSEQ + (c - 2) * 4);
            }
        };

        int buf = 0;
        issue(SLOT_B(cur), SLOT_T(cur), buf);
        while (cur < TPB) {
            int nn = cur + 1;
            while (nn < TPB && !SLOT_VALID(nn)) ++nn;
            const int b = SLOT_B(cur), t = SLOT_T(cur);
            const int nv = min(TILE, len4[cur & 3] - t * TILE);
            const int pb = b * NT + t;

            __syncthreads();                  // DMA for xs[buf] complete
            if (nn < TPB) issue(SLOT_B(nn), SLOT_T(nn), buf ^ 1);   // prefetch (hidden by MFMAs)

            // ---- A fragments: swizzled f32 reads, split to hi/lo bf16 ----
            bf16x8 ah[4], al[4];
            {
                const int row = m0 + l16;
                const float* rb = &xs[buf][0] + row * 128;
                const int sw = row & 7;
                #pragma unroll
                for (int kk = 0; kk < 4; ++kk) {
                    const int c0 = kk * 8 + quad * 2;
                    const f32x4 u = *(const f32x4*)(rb + ((c0 ^ sw) * 4));
                    const f32x4 w = *(const f32x4*)(rb + (((c0 + 1) ^ sw) * 4));
                    short8 h8, l8;
                    #pragma unroll
                    for (int j = 0; j < 4; ++j) {
                        const u16 h0 = f2bf(u[j]);
                        h8[j] = (short)h0; l8[j] = (short)f2bf(u[j] - bf2f(h0));
                        const u16 h1 = f2bf(w[j]);
                        h8[4 + j] = (short)h1; l8[4 + j] = (short)f2bf(w[j] - bf2f(h1));
                    }
                    ah[kk] = __builtin_bit_cast(bf16x8, h8);
                    al[kk] = __builtin_bit_cast(bf16x8, l8);
                }
            }

            // ---- wave-specialized B + constants ----
            const u16* bhp = packw + (isV ? 16384 : 0);
            const u16* blp = bhp + 8192;
            const float* bias = isV ? bv : bk;

            // ---- 48 MFMAs (split-bf16) ----
            float cd[4][4];
            #pragma unroll
            for (int ni = 0; ni < 4; ++ni) {
                f32x4 acc = {0.f, 0.f, 0.f, 0.f};
                #pragma unroll
                for (int kk = 0; kk < 4; ++kk) {
                    const size_t off = (size_t)((ni * 4 + kk) * 64 + lane) * 8;
                    const bf16x8 bh = *(const bf16x8*)(bhp + off);
                    const bf16x8 bl = *(const bf16x8*)(blp + off);
                    acc = __builtin_amdgcn_mfma_f32_16x16x32_bf16(ah[kk], bh, acc, 0, 0, 0);
                    acc = __builtin_amdgcn_mfma_f32_16x16x32_bf16(al[kk], bh, acc, 0, 0, 0);
                    acc = __builtin_amdgcn_mfma_f32_16x16x32_bf16(ah[kk], bl, acc, 0, 0, 0);
                }
                #pragma unroll
                for (int r = 0; r < 4; ++r)
                    cd[ni][r] = rrelu_f(acc[r] + bias[ni * 16 + l16]);
            }

            if (!isV) {
                // K path: scores, intra-quad reduce, max-free exp
                float ps[4] = {0.f, 0.f, 0.f, 0.f};
                #pragma unroll
                for (int ni = 0; ni < 4; ++ni) {
                    const float qv = qlast[b * H_ + ni * 16 + l16];
                    #pragma unroll
                    for (int r = 0; r < 4; ++r) ps[r] += qv * cd[ni][r];
                }
                #pragma unroll
                for (int mk = 1; mk < 16; mk <<= 1)
                    #pragma unroll
                    for (int r = 0; r < 4; ++r) ps[r] += __shfl_xor(ps[r], mk);
                float p4[4], ds = 0.f;
                #pragma unroll
                for (int r = 0; r < 4; ++r) {
                    const int rr = m0 + quad * 4 + r;
                    p4[r] = (rr < nv) ? __expf(fminf(ps[r], 80.f)) : 0.f;
                    ds += p4[r];
                }
                if (l16 == 0) {
                    #pragma unroll
                    for (int r = 0; r < 4; ++r) scp[m0 + quad * 4 + r] = p4[r];
                }
                ds += __shfl_xor(ds, 16);
                ds += __shfl_xor(ds, 32);
                if (lane == 0) wd[w4] = ds;
            }
            __syncthreads();                  // scp/wd ready

            if (isV) {
                // V path: p.V over this wave's 16 rows
                float pr[4];
                #pragma unroll
                for (int r = 0; r < 4; ++r) pr[r] = scp[m0 + quad * 4 + r];
                float pv[4];
                #pragma unroll
                for (int ni = 0; ni < 4; ++ni) {
                    float a = 0.f;
                    #pragma unroll
                    for (int r = 0; r < 4; ++r) a += pr[r] * cd[ni][r];
                    pv[ni] = a;
                }
                #pragma unroll
                for (int mk = 16; mk < 64; mk <<= 1)
                    #pragma unroll
                    for (int ni = 0; ni < 4; ++ni) pv[ni] += __shfl_xor(pv[ni], mk);
                if (quad == 0) {
                    #pragma unroll
                    for (int ni = 0; ni < 4; ++ni) red[w4][ni * 16 + l16] = pv[ni];
                }
            }
            __syncthreads();                  // red ready

            if (tid < H_)
                pnum[(size_t)pb * H_ + tid] =
                    red[0][tid] + red[1][tid] + red[2][tid] + red[3][tid];
            if (tid == 0)
                pden[pb] = wd[0] + wd[1] + wd[2] + wd[3];

            cur = nn;
            buf ^= 1;
        }
    }
    grid.sync();

    // ================= phase 2: combine =================
    if (blk < 64 && tid < H_) {
        const int b = blk;
        const int nt = (lengths[b] + TILE - 1) / TILE;
        float den = 0.f, num = 0.f;
        for (int t = 0; t < nt; ++t) {
            den += pden[b * NT + t];
            num += pnum[(size_t)(b * NT + t) * H_ + tid];
        }
        out[b * H_ + tid] = num / den;
    }
    #undef SLOT_B
    #undef SLOT_T
    #undef SLOT_VALID
}

extern "C" void kernel_launch(void* const* d_in, const int* in_sizes, int n_in,
                              void* d_out, int out_size, void* d_ws, size_t ws_size,
                              hipStream_t stream)
{
    const float* ts      = (const float*)d_in[0];
    const float* seq     = (const float*)d_in[1];
    const int*   lengths = (const int*)d_in[2];
    const float* Wk      = (const float*)d_in[3];
    const float* bk      = (const float*)d_in[4];
    const float* Wq      = (const float*)d_in[5];
    const float* bq      = (const float*)d_in[6];
    const float* Wv      = (const float*)d_in[7];
    const float* bv      = (const float*)d_in[8];

    float* ws    = (float*)d_ws;
    float* qlast = ws;                         // 4096 f32
    float* pden  = ws + 4096;                  // 64*32 = 2048
    float* pnum  = ws + 6144;                  // 64*32*64 = 131072
    u16*   packw = (u16*)(ws + 137216);        // contiguous 64 KB: Khi|Klo|Vhi|Vlo
    float* outp  = (float*)d_out;

    void* params[] = {
        (void*)&ts, (void*)&seq, (void*)&lengths,
        (void*)&Wk, (void*)&bk, (void*)&Wq, (void*)&bq, (void*)&Wv, (void*)&bv,
        (void*)&packw, (void*)&qlast, (void*)&pden, (void*)&pnum, (void*)&outp
    };
    hipLaunchCooperativeKernel((const void*)fused_kernel, dim3(NBLK), dim3(512),
                               params, 0, stream);
}